// Round 6
// baseline (224.484 us; speedup 1.0000x reference)
//
#include <hip/hip_runtime.h>
#include <hip/hip_bf16.h>

// B=2, T=2048, C=1024, H=16, HD=64. f32 I/O; bf16 MFMA internally, f32 accum.
//
//   0) prep (fused): x -> xb bf16; w_qkv,w_out -> bf16 W^T[N][K]
//   1) gemm_glds<EPI=1,BN=128>: qkv proj (BK=64, XOR-swizzled LDS, glds16).
//      Q pre-scaled 0.125*log2e -> qk; K -> qk; V -> vt[B,H,64,T].
//   2) attn_mfma: flash attention, static exp2 softmax (chunk-linear ->
//      exact split parallelism). 256-thr / 4-wave blocks, band map: block t
//      owns Q rows [64t,64t+64), nch=t+1. Wave w owns key-slice s=w&1
//      (32 keys as two 16-key subs) x ALL 64 q rows (Q in regs), parity
//      par=w>>1 computes chunks c&1==par. S^T per 16-key sub gives lane
//      keys quad*4+r; PV K=32 window in interleaved order
//      {sub0:quad*4+r, sub1:+16} so P feeds PV's A-frag directly from
//      registers. No P LDS round-trip; each wave reads only its 4KB slice.
//      ROUND-6: round-5 still spilled ~50MB (sv[4][2] plateau pushed peak
//      ~160 regs against the 170 cap). Chunk body reordered per-qt (sv
//      transient 8 regs, V frags transient 8) -> peak ~140; body is a
//      MACRO (no array decay across call boundary). Merge/epilogue keep
//      compile-time indices + wave-uniform guards (rule #20).
//      LDS 32KB; launch_bounds(256,3) -> 3 blocks/CU = 12 waves/CU.
//   3) gemm_glds<EPI=0,BN=64>: out proj -> d_out f32

#define B_ 2
#define T_ 2048
#define C_ 1024
#define H_ 16
#define HD_ 64
#define M_ (B_ * T_)      // 4096
#define N3_ (3 * C_)      // 3072
#define QK2_ 2048
#define QSCALE 0.18033688f   // 0.125 * log2(e)

typedef __attribute__((ext_vector_type(8))) short short8;
typedef __attribute__((ext_vector_type(4))) short short4v;
typedef __attribute__((ext_vector_type(4))) float floatx4;

__device__ __forceinline__ unsigned short f2b(float f) {
    __hip_bfloat16 h = __float2bfloat16(f);
    return *reinterpret_cast<unsigned short*>(&h);
}

__device__ __forceinline__ float fexp2(float x) {
#if __has_builtin(__builtin_amdgcn_exp2f)
    return __builtin_amdgcn_exp2f(x);
#else
    return exp2f(x);
#endif
}

__device__ __forceinline__ void glds16(const void* g, void* l) {
    __builtin_amdgcn_global_load_lds(
        (const __attribute__((address_space(1))) void*)g,
        (__attribute__((address_space(3))) void*)l, 16, 0, 0);
}

// ---------------------------------------------------------------------------
// Fused prep. seg0 (4096 blocks): x f32->bf16. seg1 (1536): w_qkv -> wt1
// [3072][1024] via 64(k)x32(n) tiles, short8 coalesced writes. seg2 (512):
// w_out -> wt2.
// ---------------------------------------------------------------------------
__global__ __launch_bounds__(256) void prep(
    const float* __restrict__ x, const float* __restrict__ w_qkv,
    const float* __restrict__ w_out, unsigned short* __restrict__ xb,
    unsigned short* __restrict__ wt1, unsigned short* __restrict__ wt2) {
    __shared__ float t[64][33];
    const int bi = blockIdx.x;
    const int tid = threadIdx.x;
    if (bi < 4096) {
        int i = (bi * 256 + tid) * 4;
        float4 v = *reinterpret_cast<const float4*>(x + i);
        short4v s;
        s[0] = (short)f2b(v.x); s[1] = (short)f2b(v.y);
        s[2] = (short)f2b(v.z); s[3] = (short)f2b(v.w);
        *reinterpret_cast<short4v*>(xb + i) = s;
        return;
    }
    const float* src; unsigned short* dst; int n0, k0, N;
    if (bi < 4096 + 1536) {
        int u = bi - 4096;
        src = w_qkv; dst = wt1; N = N3_;
        k0 = (u & 15) * 64; n0 = (u >> 4) * 32;
    } else {
        int u = bi - (4096 + 1536);
        src = w_out; dst = wt2; N = C_;
        k0 = (u & 15) * 64; n0 = (u >> 4) * 32;
    }
    const int tx = tid & 31, ty = tid >> 5;
#pragma unroll
    for (int i = 0; i < 8; i++)
        t[ty + i * 8][tx] = src[(size_t)(k0 + ty + i * 8) * N + n0 + tx];
    __syncthreads();
    const int row = tid >> 3;
    const int kp  = (tid & 7) * 8;
    short8 o;
#pragma unroll
    for (int j = 0; j < 8; j++) o[j] = (short)f2b(t[kp + j][row]);
    *reinterpret_cast<short8*>(&dst[(size_t)(n0 + row) * C_ + k0 + kp]) = o;
}

// ---------------------------------------------------------------------------
// GEMM: C[M,N] = A[M,K] @ Bt^T[N,K] + bias[N]. A,Bt bf16. Tile 128 x BN,
// BK=64, 4 waves 2x2. LDS rows 64 shorts, XOR chunk swizzle; glds16 staging.
// 1D grid, XCD-banded (neutral-at-worst heuristic).
// ---------------------------------------------------------------------------
template<int EPI, int BN>
__global__ __launch_bounds__(256) void gemm_glds(
    const unsigned short* __restrict__ A, const unsigned short* __restrict__ Bt,
    const float* __restrict__ bias, void* __restrict__ Cp,
    unsigned short* __restrict__ vtp, int M, int N, int K) {
    constexpr int NI = BN / 32;
    __shared__ __align__(16) unsigned short Al[128 * 64];
    __shared__ __align__(16) unsigned short Bl[BN * 64];

    const int tid  = threadIdx.x;
    const int lane = tid & 63;
    const int w    = tid >> 6;
    const int c16  = lane & 15;
    const int quad = lane >> 4;
    const int NT  = N / BN;
    const int pe  = NT >> 3;
    const int xcd = blockIdx.x & 7;
    const int ii  = blockIdx.x >> 3;
    const int n0  = (xcd * pe + ii % pe) * BN;
    const int m0  = (ii / pe) * 128;
    const int wm = (w >> 1) * 64;
    const int wn = (w & 1) * (BN / 2);

    floatx4 acc[4][NI] = {};

    const int srow = lane >> 3;
    const int sch  = ((lane & 7) ^ srow) * 8;
    const unsigned short* ag = A + (size_t)(m0 + w * 32 + srow) * K + sch;
    const unsigned short* bg = Bt + (size_t)(n0 + w * (BN / 4) + srow) * K + sch;

    const int s7 = c16 & 7;

    for (int k0 = 0; k0 < K; k0 += 64) {
        __syncthreads();
#pragma unroll
        for (int i = 0; i < 4; i++)
            glds16(ag + k0 + (size_t)(i * 8) * K, &Al[(w * 32 + i * 8) * 64]);
#pragma unroll
        for (int i = 0; i < BN / 32; i++)
            glds16(bg + k0 + (size_t)(i * 8) * K,
                   &Bl[(w * (BN / 4) + i * 8) * 64]);
        __syncthreads();

        short8 af[4][2], bf[NI][2];
#pragma unroll
        for (int im = 0; im < 4; im++)
#pragma unroll
            for (int kk = 0; kk < 2; kk++)
                af[im][kk] = *reinterpret_cast<const short8*>(
                    &Al[(wm + im * 16 + c16) * 64 + ((kk * 4 + quad) ^ s7) * 8]);
#pragma unroll
        for (int in = 0; in < NI; in++)
#pragma unroll
            for (int kk = 0; kk < 2; kk++)
                bf[in][kk] = *reinterpret_cast<const short8*>(
                    &Bl[(wn + in * 16 + c16) * 64 + ((kk * 4 + quad) ^ s7) * 8]);
#pragma unroll
        for (int im = 0; im < 4; im++)
#pragma unroll
            for (int in = 0; in < NI; in++)
#pragma unroll
                for (int kk = 0; kk < 2; kk++)
                    acc[im][in] = __builtin_amdgcn_mfma_f32_16x16x32_bf16(
                        af[im][kk], bf[in][kk], acc[im][in], 0, 0, 0);
    }

    const int ncol = n0 + wn;
    float bv[NI];
#pragma unroll
    for (int in = 0; in < NI; in++) bv[in] = bias[ncol + in * 16 + c16];

    if (EPI == 0) {
        float* C = (float*)Cp;
#pragma unroll
        for (int im = 0; im < 4; im++)
#pragma unroll
            for (int r = 0; r < 4; r++) {
                int row = m0 + wm + im * 16 + quad * 4 + r;
#pragma unroll
                for (int in = 0; in < NI; in++)
                    C[(size_t)row * N + ncol + in * 16 + c16] =
                        acc[im][in][r] + bv[in];
            }
    } else {
        if (ncol < 2 * C_) {
            const float fac = (ncol < C_) ? QSCALE : 1.0f;
            unsigned short* qkp = (unsigned short*)Cp;
#pragma unroll
            for (int im = 0; im < 4; im++)
#pragma unroll
                for (int r = 0; r < 4; r++) {
                    int row = m0 + wm + im * 16 + quad * 4 + r;
#pragma unroll
                    for (int in = 0; in < NI; in++)
                        qkp[(size_t)row * QK2_ + ncol + in * 16 + c16] =
                            f2b((acc[im][in][r] + bv[in]) * fac);
                }
        } else {                 // V -> vt[B,H,64,T]
#pragma unroll
            for (int im = 0; im < 4; im++) {
                int row0 = m0 + wm + im * 16 + quad * 4;
                int b  = row0 >> 11;
                int t0 = row0 & (T_ - 1);
#pragma unroll
                for (int in = 0; in < NI; in++) {
                    int dfull = ncol - 2 * C_ + in * 16 + c16;
                    short4v sv;
#pragma unroll
                    for (int r = 0; r < 4; r++)
                        sv[r] = (short)f2b(acc[im][in][r] + bv[in]);
                    *reinterpret_cast<short4v*>(
                        &vtp[(((size_t)(b << 10) + dfull) << 11) + t0]) = sv;
                }
            }
        }
    }
}

// ---------------------------------------------------------------------------
// One 64-key chunk, one wave: 32-key slice s x all 64 q rows. MACRO (no
// array decay). Per-qt: compute S^T for both 16-key subs (transient 8
// regs), exp2+pack -> pf[qt]; then per-dt: build V frag (transient 8 regs)
// and run 4 PV MFMAs. Peak regs ~140 (under the 170 cap at 3 waves/SIMD).
// ---------------------------------------------------------------------------
#define ATTN_CHUNK(MASKED, Kb, Vb, kb)                                        \
{                                                                             \
    const int sxr = c16 & 7;                                                  \
    const int ch0 = (quad ^ sxr) * 8;                                         \
    const int ch1 = ((4 + quad) ^ sxr) * 8;                                   \
    const int kr0 = (s * 32 + c16) * 64;                                      \
    const int kr1 = (s * 32 + 16 + c16) * 64;                                 \
    short8 kf00 = *reinterpret_cast<const short8*>(&(Kb)[kr0 + ch0]);         \
    short8 kf01 = *reinterpret_cast<const short8*>(&(Kb)[kr0 + ch1]);         \
    short8 kf10 = *reinterpret_cast<const short8*>(&(Kb)[kr1 + ch0]);         \
    short8 kf11 = *reinterpret_cast<const short8*>(&(Kb)[kr1 + ch1]);         \
    short8 pf[4];                                                             \
    _Pragma("unroll")                                                         \
    for (int qt = 0; qt < 4; qt++) {                                          \
        floatx4 s0 = __builtin_amdgcn_mfma_f32_16x16x32_bf16(                 \
            kf00, af[qt][0], z, 0, 0, 0);                                     \
        s0 = __builtin_amdgcn_mfma_f32_16x16x32_bf16(                         \
            kf01, af[qt][1], s0, 0, 0, 0);                                    \
        floatx4 s1 = __builtin_amdgcn_mfma_f32_16x16x32_bf16(                 \
            kf10, af[qt][0], z, 0, 0, 0);                                     \
        s1 = __builtin_amdgcn_mfma_f32_16x16x32_bf16(                         \
            kf11, af[qt][1], s1, 0, 0, 0);                                    \
        float ll = 0.f;                                                       \
        short8 p8;                                                            \
        _Pragma("unroll")                                                     \
        for (int r = 0; r < 4; r++) {                                         \
            float p0, p1;                                                     \
            if (MASKED) {                                                     \
                int key0 = (kb) + s * 32 + quad * 4 + r;                      \
                int qr = q0 + qt * 16 + c16;                                  \
                p0 = (key0 <= qr) ? fexp2(s0[r]) : 0.f;                       \
                p1 = (key0 + 16 <= qr) ? fexp2(s1[r]) : 0.f;                  \
            } else {                                                          \
                p0 = fexp2(s0[r]);                                            \
                p1 = fexp2(s1[r]);                                            \
            }                                                                 \
            ll += p0 + p1;                                                    \
            p8[r] = (short)f2b(p0);                                           \
            p8[4 + r] = (short)f2b(p1);                                       \
        }                                                                     \
        lacc[qt] += ll;                                                       \
        pf[qt] = p8;                                                          \
    }                                                                         \
    _Pragma("unroll")                                                         \
    for (int dt = 0; dt < 4; dt++) {                                          \
        const int vr = (dt * 16 + c16) * 64;                                  \
        short4v v0 = *reinterpret_cast<const short4v*>(                       \
            &(Vb)[vr + (((s * 4 + (quad >> 1)) ^ sxr) << 3) + (quad & 1) * 4]); \
        short4v v1 = *reinterpret_cast<const short4v*>(                       \
            &(Vb)[vr + (((s * 4 + 2 + (quad >> 1)) ^ sxr) << 3) + (quad & 1) * 4]); \
        short8 vv;                                                            \
        vv[0] = v0[0]; vv[1] = v0[1]; vv[2] = v0[2]; vv[3] = v0[3];           \
        vv[4] = v1[0]; vv[5] = v1[1]; vv[6] = v1[2]; vv[7] = v1[3];           \
        _Pragma("unroll")                                                     \
        for (int qt = 0; qt < 4; qt++)                                        \
            O[qt][dt] = __builtin_amdgcn_mfma_f32_16x16x32_bf16(              \
                pf[qt], vv, O[qt][dt], 0, 0, 0);                              \
    }                                                                         \
}

// ---------------------------------------------------------------------------
// Flash attention, key-sliced. Block = 256 thr = 4 waves; block t owns Q
// rows [64t,64t+64), nch=t+1, LPT. Wave w: slice s=w&1 (keys 32s..32s+32
// of each chunk, all 64 q rows, Q in regs), parity par=w>>1 computes
// chunks c&1==par (chunk-linear softmax -> exact merge by addition).
// Double-buffered K/V (32KB LDS) staged by all 4 waves, 1 barrier/chunk.
// 4-way O merge by qt-rotation through dead K/V LDS — all O[] indices
// COMPILE-TIME (unrolled qt + wave-uniform guards; rule #20). Wave w
// finishes qt=w. launch_bounds(256,3) -> 3 blocks/CU = 12 waves/CU.
// ---------------------------------------------------------------------------
__global__ __launch_bounds__(256, 3) void attn_mfma(
    const unsigned short* __restrict__ qk,
    const unsigned short* __restrict__ vt,
    unsigned short* __restrict__ y) {
    __shared__ __align__(16) unsigned short Kl[2][64 * 64];
    __shared__ __align__(16) unsigned short Vl[2][64 * 64];

    const int tid  = threadIdx.x;
    const int lane = tid & 63;
    const int w    = tid >> 6;          // 0..3
    const int s    = w & 1;             // key-slice
    const int par  = w >> 1;            // chunk parity
    const int c16  = lane & 15;
    const int quad = lane >> 4;
    const int bh = blockIdx.x & 31;
    const int t  = 31 - (blockIdx.x >> 5);   // longest-first
    const int b  = bh >> 4;
    const int h  = bh & 15;
    const int q0 = t * 64;
    const int nch = t + 1;

    const unsigned short* qrow = qk + (size_t)b * T_ * QK2_ + h * HD_;
    const unsigned short* krow = qrow + C_;
    const unsigned short* vrow = vt + ((size_t)bh << 6) * T_;

    // Q in registers: B-frags, af[qt][hh] = Q[q0+qt*16+c16][hh*32+quad*8 ..+8]
    short8 af[4][2];
#pragma unroll
    for (int qt = 0; qt < 4; qt++)
#pragma unroll
        for (int hh = 0; hh < 2; hh++)
            af[qt][hh] = *reinterpret_cast<const short8*>(
                qrow + (size_t)(q0 + qt * 16 + c16) * QK2_ + hh * 32 + quad * 8);

    floatx4 O[4][4] = {};
    float lacc[4] = {0.f, 0.f, 0.f, 0.f};
    const floatx4 z = {0.f, 0.f, 0.f, 0.f};

    const int r8 = lane >> 3;
    const int sw = ((lane & 7) ^ r8) * 8;

    // stage chunk 0 into buffer 0 (each wave: 2 K row-groups + 2 V row-groups)
#pragma unroll
    for (int i = 0; i < 2; i++) {
        glds16(krow + (size_t)(w * 16 + i * 8 + r8) * QK2_ + sw,
               &Kl[0][(w * 16 + i * 8) * 64]);
        glds16(vrow + (size_t)(w * 16 + i * 8 + r8) * T_ + sw,
               &Vl[0][(w * 16 + i * 8) * 64]);
    }

    for (int c = 0; c < nch; c++) {
        __syncthreads();       // chunk c staged; prev buf reads done
        if (c + 1 < nch) {     // prefetch chunk c+1 into the other buffer
            const int kb2 = (c + 1) * 64;
            const int nb = (c + 1) & 1;
#pragma unroll
            for (int i = 0; i < 2; i++) {
                glds16(krow + (size_t)(kb2 + w * 16 + i * 8 + r8) * QK2_ + sw,
                       &Kl[nb][(w * 16 + i * 8) * 64]);
                glds16(vrow + (size_t)(w * 16 + i * 8 + r8) * T_ + kb2 + sw,
                       &Vl[nb][(w * 16 + i * 8) * 64]);
            }
        }
        if ((c & 1) == par) {  // wave-uniform: this parity's chunk
            const int kb = c * 64;
            const unsigned short* Kb = Kl[c & 1];
            const unsigned short* Vb = Vl[c & 1];
            if (c + 1 < nch) {
                ATTN_CHUNK(0, Kb, Vb, kb)
            } else {
                ATTN_CHUNK(1, Kb, Vb, kb)
            }
        }
    }

    // ---- merge: O_total[qt] = sum over 4 waves; rotate qt through dead KV.
    // All O[] indices compile-time; guards are wave-uniform (rule #20).
    __syncthreads();                       // all K/V reads done
    float* Of = (float*)&Kl[0][0];         // 4 regions x 4KB: [qt][dt][lane][4]
    float* Lb = (float*)&Vl[0][0];         // l: [qt][w][lane]
#pragma unroll
    for (int qt = 0; qt < 4; qt++)
        Lb[qt * 256 + w * 64 + lane] = lacc[qt];
#pragma unroll
    for (int ph = 1; ph <= 3; ph++) {
#pragma unroll
        for (int qt = 0; qt < 4; qt++) {
            if (((qt - w) & 3) == ph) {    // wave w writes region (w+ph)&3
#pragma unroll
                for (int dt = 0; dt < 4; dt++)
                    *reinterpret_cast<floatx4*>(
                        &Of[qt * 1024 + dt * 256 + lane * 4]) = O[qt][dt];
            }
        }
        __syncthreads();
#pragma unroll
        for (int qt = 0; qt < 4; qt++) {
            if (qt == w) {                 // owner accumulates its region
#pragma unroll
                for (int dt = 0; dt < 4; dt++)
                    O[qt][dt] += *reinterpret_cast<const floatx4*>(
                        &Of[qt * 1024 + dt * 256 + lane * 4]);
            }
        }
        __syncthreads();
    }

    // l: sum 4 waves' partials for qt=w, then quad-reduce (q = c16 group)
    float lj = Lb[w * 256 + lane] + Lb[w * 256 + 64 + lane] +
               Lb[w * 256 + 128 + lane] + Lb[w * 256 + 192 + lane];
    lj += __shfl_xor(lj, 16);
    lj += __shfl_xor(lj, 32);
    float lr[4];
#pragma unroll
    for (int r = 0; r < 4; r++)
        lr[r] = __shfl(lj, quad * 4 + r);

    // epilogue: wave w writes q rows q0+16w+quad*4+r, cols dt*16+c16
    // (compile-time qt, uniform guard -> O stays in registers)
#pragma unroll
    for (int qt = 0; qt < 4; qt++) {
        if (qt == w) {
#pragma unroll
            for (int dt = 0; dt < 4; dt++)
#pragma unroll
                for (int r = 0; r < 4; r++) {
                    float val = O[qt][dt][r] / fmaxf(lr[r], 1e-30f);
                    y[((size_t)b * T_ + q0 + qt * 16 + quad * 4 + r) * C_ +
                      h * HD_ + dt * 16 + c16] = f2b(val);
                }
        }
    }
}

extern "C" void kernel_launch(void* const* d_in, const int* in_sizes, int n_in,
                              void* d_out, int out_size, void* d_ws, size_t ws_size,
                              hipStream_t stream) {
    const float* x     = (const float*)d_in[0];
    const float* w_qkv = (const float*)d_in[1];
    const float* b_qkv = (const float*)d_in[2];
    const float* w_out = (const float*)d_in[3];
    const float* b_out = (const float*)d_in[4];
    float* out = (float*)d_out;

    unsigned short* qkb = (unsigned short*)d_ws;                 // [4096][2048]
    unsigned short* vtb = qkb + (size_t)M_ * QK2_;               // [B,H,64,T]
    unsigned short* yb  = vtb + (size_t)B_ * H_ * HD_ * T_;      // [4096][1024]
    unsigned short* wt1 = yb + (size_t)M_ * C_;                  // [3072][1024]
    unsigned short* wt2 = wt1 + (size_t)N3_ * C_;                // [1024][1024]
    unsigned short* xb  = wt2 + (size_t)C_ * C_;                 // [4096][1024]

    prep<<<4096 + 1536 + 512, 256, 0, stream>>>(x, w_qkv, w_out, xb, wt1, wt2);

    gemm_glds<1, 128><<<(N3_ / 128) * (M_ / 128), 256, 0, stream>>>(
        xb, wt1, b_qkv, qkb, vtb, M_, N3_, C_);

    attn_mfma<<<B_ * H_ * 32, 256, 0, stream>>>(qkb, vtb, yb);

    gemm_glds<0, 64><<<(C_ / 64) * (M_ / 128), 256, 0, stream>>>(
        yb, wt2, b_out, out, nullptr, M_, C_, C_);
}

// Round 7
// 170.562 us; speedup vs baseline: 1.3161x; 1.3161x over previous
//
#include <hip/hip_runtime.h>
#include <hip/hip_bf16.h>

// B=2, T=2048, C=1024, H=16, HD=64. f32 I/O; bf16 MFMA internally, f32 accum.
//
//   0) prep (fused): x -> xb bf16; w_qkv,w_out -> bf16 W^T[N][K]
//   1) gemm_glds<EPI=1,BN=128>: qkv proj (BK=64, XOR-swizzled LDS, glds16).
//      Q pre-scaled 0.125*log2e -> qk; K -> qk; V -> vt[B,H,64,T].
//   2) attn_mfma: flash attention, static exp2 softmax. 256-thr / 4-wave
//      blocks, band map: block t owns Q rows [64t,64t+64), nch=t+1, LPT.
//      ROUND-7: 2x2 wave split. Wave w: q-half wq=w&1 (rows q0+32wq..+32,
//      2 q-tiles, Q in regs), key-half ws=w>>1 (keys 32ws..+32 of EVERY
//      chunk as two 16-key subs; no parity split). S^T per sub gives lane
//      keys quad*4+r; PV K=32 window in interleaved order {sub0:quad*4+r,
//      sub1:+16} feeds P to PV's A-frag directly from registers. No P LDS
//      round-trip; 2x K/V read redundancy (32KB/chunk/block).
//      Baseline live state HALVED vs rounds 3-6: O[2][4]=32 + af[2][2]=16
//      (was 64+32) -> peak ~110 regs, a 60-reg margin under the 170 cap
//      (estimates ran ~30 low historically -> still safe). Rounds 3-6's
//      4-qt structure spilled 50-76MB at every body ordering; this is the
//      structural fix. Pair merge (w += w+2) through dead K/V LDS, all O
//      indices compile-time (rule #20). Fully-masked {wq0,ws1} corner of
//      diagonal chunk skipped (wave-uniform).
//      LDS 32KB; launch_bounds(256,3) -> 3 blocks/CU = 12 waves/CU.
//   3) gemm_glds<EPI=0,BN=64>: out proj -> d_out f32

#define B_ 2
#define T_ 2048
#define C_ 1024
#define H_ 16
#define HD_ 64
#define M_ (B_ * T_)      // 4096
#define N3_ (3 * C_)      // 3072
#define QK2_ 2048
#define QSCALE 0.18033688f   // 0.125 * log2(e)

typedef __attribute__((ext_vector_type(8))) short short8;
typedef __attribute__((ext_vector_type(4))) short short4v;
typedef __attribute__((ext_vector_type(4))) float floatx4;

__device__ __forceinline__ unsigned short f2b(float f) {
    __hip_bfloat16 h = __float2bfloat16(f);
    return *reinterpret_cast<unsigned short*>(&h);
}

__device__ __forceinline__ float fexp2(float x) {
#if __has_builtin(__builtin_amdgcn_exp2f)
    return __builtin_amdgcn_exp2f(x);
#else
    return exp2f(x);
#endif
}

__device__ __forceinline__ void glds16(const void* g, void* l) {
    __builtin_amdgcn_global_load_lds(
        (const __attribute__((address_space(1))) void*)g,
        (__attribute__((address_space(3))) void*)l, 16, 0, 0);
}

// ---------------------------------------------------------------------------
// Fused prep. seg0 (4096 blocks): x f32->bf16. seg1 (1536): w_qkv -> wt1
// [3072][1024] via 64(k)x32(n) tiles, short8 coalesced writes. seg2 (512):
// w_out -> wt2.
// ---------------------------------------------------------------------------
__global__ __launch_bounds__(256) void prep(
    const float* __restrict__ x, const float* __restrict__ w_qkv,
    const float* __restrict__ w_out, unsigned short* __restrict__ xb,
    unsigned short* __restrict__ wt1, unsigned short* __restrict__ wt2) {
    __shared__ float t[64][33];
    const int bi = blockIdx.x;
    const int tid = threadIdx.x;
    if (bi < 4096) {
        int i = (bi * 256 + tid) * 4;
        float4 v = *reinterpret_cast<const float4*>(x + i);
        short4v s;
        s[0] = (short)f2b(v.x); s[1] = (short)f2b(v.y);
        s[2] = (short)f2b(v.z); s[3] = (short)f2b(v.w);
        *reinterpret_cast<short4v*>(xb + i) = s;
        return;
    }
    const float* src; unsigned short* dst; int n0, k0, N;
    if (bi < 4096 + 1536) {
        int u = bi - 4096;
        src = w_qkv; dst = wt1; N = N3_;
        k0 = (u & 15) * 64; n0 = (u >> 4) * 32;
    } else {
        int u = bi - (4096 + 1536);
        src = w_out; dst = wt2; N = C_;
        k0 = (u & 15) * 64; n0 = (u >> 4) * 32;
    }
    const int tx = tid & 31, ty = tid >> 5;
#pragma unroll
    for (int i = 0; i < 8; i++)
        t[ty + i * 8][tx] = src[(size_t)(k0 + ty + i * 8) * N + n0 + tx];
    __syncthreads();
    const int row = tid >> 3;
    const int kp  = (tid & 7) * 8;
    short8 o;
#pragma unroll
    for (int j = 0; j < 8; j++) o[j] = (short)f2b(t[kp + j][row]);
    *reinterpret_cast<short8*>(&dst[(size_t)(n0 + row) * C_ + k0 + kp]) = o;
}

// ---------------------------------------------------------------------------
// GEMM: C[M,N] = A[M,K] @ Bt^T[N,K] + bias[N]. A,Bt bf16. Tile 128 x BN,
// BK=64, 4 waves 2x2. LDS rows 64 shorts, XOR chunk swizzle; glds16 staging.
// 1D grid, XCD-banded (neutral-at-worst heuristic).
// ---------------------------------------------------------------------------
template<int EPI, int BN>
__global__ __launch_bounds__(256) void gemm_glds(
    const unsigned short* __restrict__ A, const unsigned short* __restrict__ Bt,
    const float* __restrict__ bias, void* __restrict__ Cp,
    unsigned short* __restrict__ vtp, int M, int N, int K) {
    constexpr int NI = BN / 32;
    __shared__ __align__(16) unsigned short Al[128 * 64];
    __shared__ __align__(16) unsigned short Bl[BN * 64];

    const int tid  = threadIdx.x;
    const int lane = tid & 63;
    const int w    = tid >> 6;
    const int c16  = lane & 15;
    const int quad = lane >> 4;
    const int NT  = N / BN;
    const int pe  = NT >> 3;
    const int xcd = blockIdx.x & 7;
    const int ii  = blockIdx.x >> 3;
    const int n0  = (xcd * pe + ii % pe) * BN;
    const int m0  = (ii / pe) * 128;
    const int wm = (w >> 1) * 64;
    const int wn = (w & 1) * (BN / 2);

    floatx4 acc[4][NI] = {};

    const int srow = lane >> 3;
    const int sch  = ((lane & 7) ^ srow) * 8;
    const unsigned short* ag = A + (size_t)(m0 + w * 32 + srow) * K + sch;
    const unsigned short* bg = Bt + (size_t)(n0 + w * (BN / 4) + srow) * K + sch;

    const int s7 = c16 & 7;

    for (int k0 = 0; k0 < K; k0 += 64) {
        __syncthreads();
#pragma unroll
        for (int i = 0; i < 4; i++)
            glds16(ag + k0 + (size_t)(i * 8) * K, &Al[(w * 32 + i * 8) * 64]);
#pragma unroll
        for (int i = 0; i < BN / 32; i++)
            glds16(bg + k0 + (size_t)(i * 8) * K,
                   &Bl[(w * (BN / 4) + i * 8) * 64]);
        __syncthreads();

        short8 af[4][2], bf[NI][2];
#pragma unroll
        for (int im = 0; im < 4; im++)
#pragma unroll
            for (int kk = 0; kk < 2; kk++)
                af[im][kk] = *reinterpret_cast<const short8*>(
                    &Al[(wm + im * 16 + c16) * 64 + ((kk * 4 + quad) ^ s7) * 8]);
#pragma unroll
        for (int in = 0; in < NI; in++)
#pragma unroll
            for (int kk = 0; kk < 2; kk++)
                bf[in][kk] = *reinterpret_cast<const short8*>(
                    &Bl[(wn + in * 16 + c16) * 64 + ((kk * 4 + quad) ^ s7) * 8]);
#pragma unroll
        for (int im = 0; im < 4; im++)
#pragma unroll
            for (int in = 0; in < NI; in++)
#pragma unroll
                for (int kk = 0; kk < 2; kk++)
                    acc[im][in] = __builtin_amdgcn_mfma_f32_16x16x32_bf16(
                        af[im][kk], bf[in][kk], acc[im][in], 0, 0, 0);
    }

    const int ncol = n0 + wn;
    float bv[NI];
#pragma unroll
    for (int in = 0; in < NI; in++) bv[in] = bias[ncol + in * 16 + c16];

    if (EPI == 0) {
        float* C = (float*)Cp;
#pragma unroll
        for (int im = 0; im < 4; im++)
#pragma unroll
            for (int r = 0; r < 4; r++) {
                int row = m0 + wm + im * 16 + quad * 4 + r;
#pragma unroll
                for (int in = 0; in < NI; in++)
                    C[(size_t)row * N + ncol + in * 16 + c16] =
                        acc[im][in][r] + bv[in];
            }
    } else {
        if (ncol < 2 * C_) {
            const float fac = (ncol < C_) ? QSCALE : 1.0f;
            unsigned short* qkp = (unsigned short*)Cp;
#pragma unroll
            for (int im = 0; im < 4; im++)
#pragma unroll
                for (int r = 0; r < 4; r++) {
                    int row = m0 + wm + im * 16 + quad * 4 + r;
#pragma unroll
                    for (int in = 0; in < NI; in++)
                        qkp[(size_t)row * QK2_ + ncol + in * 16 + c16] =
                            f2b((acc[im][in][r] + bv[in]) * fac);
                }
        } else {                 // V -> vt[B,H,64,T]
#pragma unroll
            for (int im = 0; im < 4; im++) {
                int row0 = m0 + wm + im * 16 + quad * 4;
                int b  = row0 >> 11;
                int t0 = row0 & (T_ - 1);
#pragma unroll
                for (int in = 0; in < NI; in++) {
                    int dfull = ncol - 2 * C_ + in * 16 + c16;
                    short4v sv;
#pragma unroll
                    for (int r = 0; r < 4; r++)
                        sv[r] = (short)f2b(acc[im][in][r] + bv[in]);
                    *reinterpret_cast<short4v*>(
                        &vtp[(((size_t)(b << 10) + dfull) << 11) + t0]) = sv;
                }
            }
        }
    }
}

// ---------------------------------------------------------------------------
// One 64-key chunk, one wave: key-half ws (subs at 32ws, 32ws+16) x this
// wave's 32 q rows (2 tiles). MACRO (no array decay). S^T per sub: lane
// holds P[q=c16+16qt+32wq][key=32ws+16sub+quad*4+r]; exp2+pack -> pf[qt];
// PV K=32 window in interleaved order {sub0:quad*4+r, sub1:+16}: pf feeds
// A-frag directly; V B-frag = 2 x b64 per dt in the same order.
// ---------------------------------------------------------------------------
#define ATTN_CHUNK(MASKED, Kb, Vb, kb)                                        \
{                                                                             \
    const int sxr = c16 & 7;                                                  \
    const int ch0 = (quad ^ sxr) * 8;                                         \
    const int ch1 = ((4 + quad) ^ sxr) * 8;                                   \
    const int kr0 = (ws * 32 + c16) * 64;                                     \
    const int kr1 = (ws * 32 + 16 + c16) * 64;                                \
    short8 kf00 = *reinterpret_cast<const short8*>(&(Kb)[kr0 + ch0]);         \
    short8 kf01 = *reinterpret_cast<const short8*>(&(Kb)[kr0 + ch1]);         \
    short8 kf10 = *reinterpret_cast<const short8*>(&(Kb)[kr1 + ch0]);         \
    short8 kf11 = *reinterpret_cast<const short8*>(&(Kb)[kr1 + ch1]);         \
    short8 pf[2];                                                             \
    _Pragma("unroll")                                                         \
    for (int qt = 0; qt < 2; qt++) {                                          \
        floatx4 s0 = __builtin_amdgcn_mfma_f32_16x16x32_bf16(                 \
            kf00, af[qt][0], z, 0, 0, 0);                                     \
        s0 = __builtin_amdgcn_mfma_f32_16x16x32_bf16(                         \
            kf01, af[qt][1], s0, 0, 0, 0);                                    \
        floatx4 s1 = __builtin_amdgcn_mfma_f32_16x16x32_bf16(                 \
            kf10, af[qt][0], z, 0, 0, 0);                                     \
        s1 = __builtin_amdgcn_mfma_f32_16x16x32_bf16(                         \
            kf11, af[qt][1], s1, 0, 0, 0);                                    \
        float ll = 0.f;                                                       \
        short8 p8;                                                            \
        _Pragma("unroll")                                                     \
        for (int r = 0; r < 4; r++) {                                         \
            float p0, p1;                                                     \
            if (MASKED) {                                                     \
                int key0 = (kb) + ws * 32 + quad * 4 + r;                     \
                int qr = q0 + wq * 32 + qt * 16 + c16;                        \
                p0 = (key0 <= qr) ? fexp2(s0[r]) : 0.f;                       \
                p1 = (key0 + 16 <= qr) ? fexp2(s1[r]) : 0.f;                  \
            } else {                                                          \
                p0 = fexp2(s0[r]);                                            \
                p1 = fexp2(s1[r]);                                            \
            }                                                                 \
            ll += p0 + p1;                                                    \
            p8[r] = (short)f2b(p0);                                           \
            p8[4 + r] = (short)f2b(p1);                                       \
        }                                                                     \
        lacc[qt] += ll;                                                       \
        pf[qt] = p8;                                                          \
    }                                                                         \
    _Pragma("unroll")                                                         \
    for (int dt = 0; dt < 4; dt++) {                                          \
        const int vr = (dt * 16 + c16) * 64;                                  \
        short4v v0 = *reinterpret_cast<const short4v*>(                       \
            &(Vb)[vr + (((ws * 4 + (quad >> 1)) ^ sxr) << 3) + (quad & 1) * 4]); \
        short4v v1 = *reinterpret_cast<const short4v*>(                       \
            &(Vb)[vr + (((ws * 4 + 2 + (quad >> 1)) ^ sxr) << 3) + (quad & 1) * 4]); \
        short8 vv;                                                            \
        vv[0] = v0[0]; vv[1] = v0[1]; vv[2] = v0[2]; vv[3] = v0[3];           \
        vv[4] = v1[0]; vv[5] = v1[1]; vv[6] = v1[2]; vv[7] = v1[3];           \
        _Pragma("unroll")                                                     \
        for (int qt = 0; qt < 2; qt++)                                        \
            O[qt][dt] = __builtin_amdgcn_mfma_f32_16x16x32_bf16(              \
                pf[qt], vv, O[qt][dt], 0, 0, 0);                              \
    }                                                                         \
}

// ---------------------------------------------------------------------------
// Flash attention, 2x2 wave split. Block = 256 thr = 4 waves; block t owns
// Q rows [64t,64t+64), nch=t+1, LPT. Wave w: q-half wq=w&1 (32 rows, Q in
// regs), key-half ws=w>>1 (keys 32ws..+32 of EVERY chunk). Double-buffered
// K/V (32KB LDS) staged by all 4 waves, 1 barrier/chunk. Pair merge: waves
// ws=1 park O (32 f32/lane) + l in dead K/V LDS; ws=0 partners add and
// write. All O/lacc indices compile-time (rule #20). Peak ~110 VGPR under
// launch_bounds(256,3) cap ~170 -> 3 blocks/CU = 12 waves/CU, no spill.
// ---------------------------------------------------------------------------
__global__ __launch_bounds__(256, 3) void attn_mfma(
    const unsigned short* __restrict__ qk,
    const unsigned short* __restrict__ vt,
    unsigned short* __restrict__ y) {
    __shared__ __align__(16) unsigned short Kl[2][64 * 64];
    __shared__ __align__(16) unsigned short Vl[2][64 * 64];

    const int tid  = threadIdx.x;
    const int lane = tid & 63;
    const int w    = tid >> 6;          // 0..3
    const int wq   = w & 1;             // q-half
    const int ws   = w >> 1;            // key-half
    const int c16  = lane & 15;
    const int quad = lane >> 4;
    const int bh = blockIdx.x & 31;
    const int t  = 31 - (blockIdx.x >> 5);   // longest-first
    const int b  = bh >> 4;
    const int h  = bh & 15;
    const int q0 = t * 64;
    const int nch = t + 1;

    const unsigned short* qrow = qk + (size_t)b * T_ * QK2_ + h * HD_;
    const unsigned short* krow = qrow + C_;
    const unsigned short* vrow = vt + ((size_t)bh << 6) * T_;

    // Q in registers: af[qt][hh] = Q[q0+wq*32+qt*16+c16][hh*32+quad*8 ..+8]
    short8 af[2][2];
#pragma unroll
    for (int qt = 0; qt < 2; qt++)
#pragma unroll
        for (int hh = 0; hh < 2; hh++)
            af[qt][hh] = *reinterpret_cast<const short8*>(
                qrow + (size_t)(q0 + wq * 32 + qt * 16 + c16) * QK2_ +
                hh * 32 + quad * 8);

    floatx4 O[2][4] = {};
    float lacc[2] = {0.f, 0.f};
    const floatx4 z = {0.f, 0.f, 0.f, 0.f};

    const int r8 = lane >> 3;
    const int sw = ((lane & 7) ^ r8) * 8;

    // stage chunk 0 into buffer 0 (each wave: 2 K row-groups + 2 V row-groups)
#pragma unroll
    for (int i = 0; i < 2; i++) {
        glds16(krow + (size_t)(w * 16 + i * 8 + r8) * QK2_ + sw,
               &Kl[0][(w * 16 + i * 8) * 64]);
        glds16(vrow + (size_t)(w * 16 + i * 8 + r8) * T_ + sw,
               &Vl[0][(w * 16 + i * 8) * 64]);
    }

    for (int c = 0; c < nch; c++) {
        __syncthreads();       // chunk c staged; prev buf reads done
        if (c + 1 < nch) {     // prefetch chunk c+1 into the other buffer
            const int kb2 = (c + 1) * 64;
            const int nb = (c + 1) & 1;
#pragma unroll
            for (int i = 0; i < 2; i++) {
                glds16(krow + (size_t)(kb2 + w * 16 + i * 8 + r8) * QK2_ + sw,
                       &Kl[nb][(w * 16 + i * 8) * 64]);
                glds16(vrow + (size_t)(w * 16 + i * 8 + r8) * T_ + kb2 + sw,
                       &Vl[nb][(w * 16 + i * 8) * 64]);
            }
        }
        const int kb = c * 64;
        const unsigned short* Kb = Kl[c & 1];
        const unsigned short* Vb = Vl[c & 1];
        if (c + 1 < nch) {
            ATTN_CHUNK(0, Kb, Vb, kb)
        } else if (!(wq == 0 && ws == 1)) {
            // diagonal chunk; {wq0,ws1} corner is fully masked -> skip
            ATTN_CHUNK(1, Kb, Vb, kb)
        }
    }

    // ---- pair merge: O_total = O(ws=0) + O(ws=1) per q-half, through dead
    // K/V LDS. All O/lacc indices compile-time; ws/wq only in addresses.
    __syncthreads();                       // all K/V reads done
    float* Of = (float*)&Kl[0][0];         // 2 regions x 2048 f: [wq][qt][dt][lane][4]
    float* Lb = (float*)&Vl[0][0];         // l: [wq][qt][lane]
    if (ws) {
#pragma unroll
        for (int qt = 0; qt < 2; qt++) {
#pragma unroll
            for (int dt = 0; dt < 4; dt++)
                *reinterpret_cast<floatx4*>(
                    &Of[wq * 2048 + qt * 1024 + dt * 256 + lane * 4]) = O[qt][dt];
            Lb[wq * 128 + qt * 64 + lane] = lacc[qt];
        }
    }
    __syncthreads();
    if (ws == 0) {
#pragma unroll
        for (int qt = 0; qt < 2; qt++) {
#pragma unroll
            for (int dt = 0; dt < 4; dt++)
                O[qt][dt] += *reinterpret_cast<const floatx4*>(
                    &Of[wq * 2048 + qt * 1024 + dt * 256 + lane * 4]);
            float lj = lacc[qt] + Lb[wq * 128 + qt * 64 + lane];
            // per-lane partial (row c16, this lane's keys) -> row sum
            lj += __shfl_xor(lj, 16);
            lj += __shfl_xor(lj, 32);
            float lr[4];
#pragma unroll
            for (int r = 0; r < 4; r++)
                lr[r] = __shfl(lj, quad * 4 + r);

            // write rows q0+wq*32+qt*16+quad*4+r, cols h*HD+dt*16+c16
#pragma unroll
            for (int dt = 0; dt < 4; dt++)
#pragma unroll
                for (int r = 0; r < 4; r++) {
                    float val = O[qt][dt][r] / fmaxf(lr[r], 1e-30f);
                    y[((size_t)b * T_ + q0 + wq * 32 + qt * 16 + quad * 4 + r)
                          * C_ + h * HD_ + dt * 16 + c16] = f2b(val);
                }
        }
    }
}

extern "C" void kernel_launch(void* const* d_in, const int* in_sizes, int n_in,
                              void* d_out, int out_size, void* d_ws, size_t ws_size,
                              hipStream_t stream) {
    const float* x     = (const float*)d_in[0];
    const float* w_qkv = (const float*)d_in[1];
    const float* b_qkv = (const float*)d_in[2];
    const float* w_out = (const float*)d_in[3];
    const float* b_out = (const float*)d_in[4];
    float* out = (float*)d_out;

    unsigned short* qkb = (unsigned short*)d_ws;                 // [4096][2048]
    unsigned short* vtb = qkb + (size_t)M_ * QK2_;               // [B,H,64,T]
    unsigned short* yb  = vtb + (size_t)B_ * H_ * HD_ * T_;      // [4096][1024]
    unsigned short* wt1 = yb + (size_t)M_ * C_;                  // [3072][1024]
    unsigned short* wt2 = wt1 + (size_t)N3_ * C_;                // [1024][1024]
    unsigned short* xb  = wt2 + (size_t)C_ * C_;                 // [4096][1024]

    prep<<<4096 + 1536 + 512, 256, 0, stream>>>(x, w_qkv, w_out, xb, wt1, wt2);

    gemm_glds<1, 128><<<(N3_ / 128) * (M_ / 128), 256, 0, stream>>>(
        xb, wt1, b_qkv, qkb, vtb, M_, N3_, C_);

    attn_mfma<<<B_ * H_ * 32, 256, 0, stream>>>(qkb, vtb, yb);

    gemm_glds<0, 64><<<(C_ / 64) * (M_ / 128), 256, 0, stream>>>(
        yb, wt2, b_out, out, nullptr, M_, C_, C_);
}